// Round 10
// baseline (459.733 us; speedup 1.0000x reference)
//
#include <hip/hip_runtime.h>

// ---------------------------------------------------------------------------
// GIN model. R10 = R9 +:
//  - k_agg: nontemporal sedge loads + pooled stores (keep per-XCD L2 for the
//    h-row gathers, which have avg 16x reuse; streams were evicting them)
//  - k_mlp: W2 register-prefetch before GEMM1 (hides restage latency)
//  - weight preps merged into one dispatch (z-select)
//  - k_pool_all: nontemporal feat loads
// Numerics unchanged: bf16 activations, RNE bf16 MLP W, split-bf16 lin1 W.
// ---------------------------------------------------------------------------

typedef __bf16 bf16x8 __attribute__((ext_vector_type(8)));
typedef float f32x4 __attribute__((ext_vector_type(4)));

static inline int ceil_div(int a, int b) { return (a + b - 1) / b; }

__device__ inline ushort bf_rne(float v) {
  unsigned u = __float_as_uint(v);
  return (ushort)((u + 0x7fffu + ((u >> 16) & 1u)) >> 16);
}
__device__ inline float bf2f(ushort u) { return __uint_as_float((unsigned)u << 16); }
__device__ inline float bf2f_lo(unsigned g) { return __uint_as_float(g << 16); }
__device__ inline float bf2f_hi(unsigned g) { return __uint_as_float(g & 0xffff0000u); }

// ---- CSR build ------------------------------------------------------------
__global__ void k_hist(const int* __restrict__ src, int* __restrict__ deg, int E) {
  int i = blockIdx.x * blockDim.x + threadIdx.x;
  if (i < E) atomicAdd(&deg[src[i]], 1);
}

__global__ __launch_bounds__(256) void k_scan1(const int* __restrict__ deg,
                                               int* __restrict__ excl,
                                               int* __restrict__ bsum, int N) {
  __shared__ int tsum[256];
  int b = blockIdx.x, t = threadIdx.x;
  int base = b * 1024 + t * 4;
  int v0 = 0, v1 = 0, v2 = 0, v3 = 0;
  if (base + 3 < N) {
    int4 q = *(const int4*)&deg[base];
    v0 = q.x; v1 = q.y; v2 = q.z; v3 = q.w;
  } else {
    if (base + 0 < N) v0 = deg[base + 0];
    if (base + 1 < N) v1 = deg[base + 1];
    if (base + 2 < N) v2 = deg[base + 2];
    if (base + 3 < N) v3 = deg[base + 3];
  }
  tsum[t] = v0 + v1 + v2 + v3;
  __syncthreads();
  for (int off = 1; off < 256; off <<= 1) {
    int x = (t >= off) ? tsum[t - off] : 0;
    __syncthreads();
    tsum[t] += x;
    __syncthreads();
  }
  int pre = (t == 0) ? 0 : tsum[t - 1];
  if (base < N)     excl[base]     = pre;
  if (base + 1 < N) excl[base + 1] = pre + v0;
  if (base + 2 < N) excl[base + 2] = pre + v0 + v1;
  if (base + 3 < N) excl[base + 3] = pre + v0 + v1 + v2;
  if (t == 255) bsum[b] = tsum[255];
}

// merged: scans bsum (nb<=256) in LDS per block, then applies offsets
__global__ __launch_bounds__(256) void k_scan3(const int* __restrict__ excl,
                                               const int* __restrict__ bsum, int nb,
                                               int* __restrict__ rowptr,
                                               int* __restrict__ cursor, int N) {
  __shared__ int s[256];
  int t = threadIdx.x;
  s[t] = (t < nb) ? bsum[t] : 0;
  __syncthreads();
  for (int off = 1; off < 256; off <<= 1) {
    int x = (t >= off) ? s[t - off] : 0;
    __syncthreads();
    s[t] += x;
    __syncthreads();
  }
  int i = blockIdx.x * 256 + t;
  if (i < N) {
    int blk = i >> 10;
    int boff = blk ? s[blk - 1] : 0;
    int v = excl[i] + boff;
    rowptr[i] = v;
    cursor[i] = v;
  }
  if (i == N - 1) rowptr[N] = s[nb - 1];
}

__global__ void k_scatter(const int* __restrict__ src, const int* __restrict__ dst,
                          const float* __restrict__ mask, int* __restrict__ cursor,
                          int2* __restrict__ sedge, int E) {
  int i = blockIdx.x * blockDim.x + threadIdx.x;
  if (i < E) {
    int s = src[i];
    int p = atomicAdd(&cursor[s], 1);
    sedge[p] = make_int2(dst[i], __float_as_int(mask[i]));
  }
}

// ---- fp32 -> bf16 conversion ---------------------------------------------
__global__ __launch_bounds__(256) void k_tobf16(const float* __restrict__ in,
                                                ushort* __restrict__ out, int n) {
  int base = (blockIdx.x * 256 + threadIdx.x) * 4;
  if (base + 3 < n) {
    float4 v = *(const float4*)&in[base];
    ushort4 o;
    o.x = bf_rne(v.x); o.y = bf_rne(v.y); o.z = bf_rne(v.z); o.w = bf_rne(v.w);
    *(ushort4*)&out[base] = o;
  } else {
    for (int k = base; k < n; ++k) out[k] = bf_rne(in[k]);
  }
}

// ---- merged weight prep: z<2L -> MLP mats (4x4 tiles); z==2L -> lin1 ------
// grid (F/32, F/32, 2L+1); MLP layers only use blockIdx.x/y < 4.
__global__ __launch_bounds__(256) void k_prep_all(
    const float* __restrict__ W1, const float* __restrict__ W2,
    const float* __restrict__ L1W,
    ushort* __restrict__ hi1, ushort* __restrict__ hi2,
    ushort* __restrict__ l1hi, ushort* __restrict__ l1lo, int L, int F) {
  __shared__ float t[32][33];
  int z = blockIdx.z;
  int tx = threadIdx.x & 31, ty = threadIdx.x >> 5;
  if (z < 2 * L) {
    if (blockIdx.x >= 4 || blockIdx.y >= 4) return;
    const float* Wm = (z < L) ? (W1 + (size_t)z * 128 * 128)
                              : (W2 + (size_t)(z - L) * 128 * 128);
    ushort* him = (z < L) ? (hi1 + (size_t)z * 128 * 128)
                          : (hi2 + (size_t)(z - L) * 128 * 128);
    int k0 = blockIdx.x * 32, n0 = blockIdx.y * 32;
#pragma unroll
    for (int r = 0; r < 32; r += 8)
      t[ty + r][tx] = Wm[(size_t)(k0 + ty + r) * 128 + n0 + tx];
    __syncthreads();
#pragma unroll
    for (int r = 0; r < 32; r += 8)
      him[(size_t)(n0 + ty + r) * 128 + k0 + tx] = bf_rne(t[tx][ty + r]);
  } else {
    int k0 = blockIdx.x * 32, n0 = blockIdx.y * 32;
#pragma unroll
    for (int r = 0; r < 32; r += 8)
      t[ty + r][tx] = L1W[(size_t)(k0 + ty + r) * F + n0 + tx];
    __syncthreads();
#pragma unroll
    for (int r = 0; r < 32; r += 8) {
      float v = t[tx][ty + r];
      size_t o = (size_t)(n0 + ty + r) * F + k0 + tx;
      ushort h = bf_rne(v);
      l1hi[o] = h;
      l1lo[o] = bf_rne(v - bf2f(h));
    }
  }
}

// ---- per-node aggregation: 1 wave per node; nontemporal edge/out streams --
__global__ __launch_bounds__(128) void k_agg(const ushort* __restrict__ h,
                                             const int* __restrict__ rowptr,
                                             const int2* __restrict__ sedge,
                                             const float* __restrict__ eps, int layer,
                                             ushort* __restrict__ pooled, int N) {
  int v = blockIdx.x * 2 + (threadIdx.x >> 6);
  int lane = threadIdx.x & 63;
  if (v >= N) return;
  int beg = rowptr[v], end = rowptr[v + 1];
  float ax[8] = {}, ay[8] = {};
  int j = beg;
  for (; j + 8 <= end; j += 8) {
    long long e[8];
    unsigned g[8];
#pragma unroll
    for (int q = 0; q < 8; ++q)
      e[q] = __builtin_nontemporal_load((const long long*)(sedge + j + q));
#pragma unroll
    for (int q = 0; q < 8; ++q) {
      int d = (int)(unsigned)e[q];
      g[q] = *(const unsigned*)&h[(size_t)d * 128 + lane * 2];
    }
#pragma unroll
    for (int q = 0; q < 8; ++q) {
      float m = __int_as_float((int)(e[q] >> 32));
      ax[q] = fmaf(m, bf2f_lo(g[q]), ax[q]);
      ay[q] = fmaf(m, bf2f_hi(g[q]), ay[q]);
    }
  }
  for (; j + 2 <= end; j += 2) {
    long long e0 = __builtin_nontemporal_load((const long long*)(sedge + j));
    long long e1 = __builtin_nontemporal_load((const long long*)(sedge + j + 1));
    unsigned g0 = *(const unsigned*)&h[(size_t)(int)(unsigned)e0 * 128 + lane * 2];
    unsigned g1 = *(const unsigned*)&h[(size_t)(int)(unsigned)e1 * 128 + lane * 2];
    float m0 = __int_as_float((int)(e0 >> 32));
    float m1 = __int_as_float((int)(e1 >> 32));
    ax[0] = fmaf(m0, bf2f_lo(g0), ax[0]);
    ay[0] = fmaf(m0, bf2f_hi(g0), ay[0]);
    ax[1] = fmaf(m1, bf2f_lo(g1), ax[1]);
    ay[1] = fmaf(m1, bf2f_hi(g1), ay[1]);
  }
  if (j < end) {
    long long e = __builtin_nontemporal_load((const long long*)(sedge + j));
    unsigned g = *(const unsigned*)&h[(size_t)(int)(unsigned)e * 128 + lane * 2];
    float m = __int_as_float((int)(e >> 32));
    ax[0] = fmaf(m, bf2f_lo(g), ax[0]);
    ay[0] = fmaf(m, bf2f_hi(g), ay[0]);
  }
  float sx = ((ax[0] + ax[1]) + (ax[2] + ax[3])) + ((ax[4] + ax[5]) + (ax[6] + ax[7]));
  float sy = ((ay[0] + ay[1]) + (ay[2] + ay[3])) + ((ay[4] + ay[5]) + (ay[6] + ay[7]));
  float ep = 1.0f + eps[layer];
  unsigned gs = *(const unsigned*)&h[(size_t)v * 128 + lane * 2];
  sx = fmaf(ep, bf2f_lo(gs), sx);
  sy = fmaf(ep, bf2f_hi(gs), sy);
  unsigned outw = (unsigned)bf_rne(sx) | ((unsigned)bf_rne(sy) << 16);
  __builtin_nontemporal_store(outw, (unsigned*)&pooled[(size_t)v * 128 + lane * 2]);
}

// ---- fused 2-layer MLP: h_out = relu(relu(pooled@W1+b1)@W2+b2) ------------
// A-frags direct from global (L1-hot). W2 prefetched to registers during
// GEMM1. LDS: Ws 32K + H1s 16K = 48KB -> 3 blocks/CU.
__global__ __launch_bounds__(256) void k_mlp(
    const ushort* __restrict__ pooled,
    const ushort* __restrict__ w1t, const float* __restrict__ b1,
    const ushort* __restrict__ w2t, const float* __restrict__ b2,
    ushort* __restrict__ hout, int N) {
  __shared__ ushort Ws[128][128];
  __shared__ ushort H1s[64][128];
  int tid = threadIdx.x;
  int w = tid >> 6, lane = tid & 63;
  int row0 = blockIdx.x * 64;
  int wr = w >> 1, wc = w & 1;

  // stage W1
#pragma unroll
  for (int i = 0; i < 8; ++i) {
    int f = i * 256 + tid;
    int r = f >> 4, c8 = (f & 15) * 8;
    *(bf16x8*)&Ws[r][c8 ^ ((r & 7) << 3)] = *(const bf16x8*)&w1t[(size_t)r * 128 + c8];
  }
  // issue W2 loads early (land in registers while GEMM1 runs)
  bf16x8 w2r[8];
#pragma unroll
  for (int i = 0; i < 8; ++i) {
    int f = i * 256 + tid;
    int r = f >> 4, c8 = (f & 15) * 8;
    w2r[i] = *(const bf16x8*)&w2t[(size_t)r * 128 + c8];
  }
  __syncthreads();

  // GEMM1: waves 2x2, each 32 rows x 64 cols; A direct from global
  f32x4 acc[2][4];
#pragma unroll
  for (int m = 0; m < 2; ++m)
#pragma unroll
    for (int n = 0; n < 4; ++n) acc[m][n] = (f32x4){0.f, 0.f, 0.f, 0.f};
#pragma unroll
  for (int ks = 0; ks < 4; ++ks) {
    int kk = ks * 32 + (lane >> 4) * 8;
    bf16x8 a[2], b[4];
#pragma unroll
    for (int m = 0; m < 2; ++m) {
      int arow = row0 + wr * 32 + m * 16 + (lane & 15);
      if (arow >= N) arow = N - 1;
      a[m] = *(const bf16x8*)&pooled[(size_t)arow * 128 + kk];
    }
#pragma unroll
    for (int n = 0; n < 4; ++n) {
      int r = wc * 64 + n * 16 + (lane & 15);
      b[n] = *(bf16x8*)&Ws[r][kk ^ ((r & 7) << 3)];
    }
#pragma unroll
    for (int m = 0; m < 2; ++m)
#pragma unroll
      for (int n = 0; n < 4; ++n)
        acc[m][n] = __builtin_amdgcn_mfma_f32_16x16x32_bf16(a[m], b[n], acc[m][n], 0, 0, 0);
  }
#pragma unroll
  for (int m = 0; m < 2; ++m) {
    int rbase = wr * 32 + m * 16 + (lane >> 4) * 4;
#pragma unroll
    for (int n = 0; n < 4; ++n) {
      int col = wc * 64 + n * 16 + (lane & 15);
      float bb = b1[col];
#pragma unroll
      for (int r = 0; r < 4; ++r) {
        int row = rbase + r;
        float v = fmaxf(acc[m][n][r] + bb, 0.f);
        H1s[row][col ^ ((row & 7) << 3)] = bf_rne(v);
      }
    }
  }
  __syncthreads();

  // write prefetched W2 over Ws
#pragma unroll
  for (int i = 0; i < 8; ++i) {
    int f = i * 256 + tid;
    int r = f >> 4, c8 = (f & 15) * 8;
    *(bf16x8*)&Ws[r][c8 ^ ((r & 7) << 3)] = w2r[i];
  }
  __syncthreads();

  // GEMM2
#pragma unroll
  for (int m = 0; m < 2; ++m)
#pragma unroll
    for (int n = 0; n < 4; ++n) acc[m][n] = (f32x4){0.f, 0.f, 0.f, 0.f};
#pragma unroll
  for (int ks = 0; ks < 4; ++ks) {
    int kk = ks * 32 + (lane >> 4) * 8;
    bf16x8 a[2], b[4];
#pragma unroll
    for (int m = 0; m < 2; ++m) {
      int r = wr * 32 + m * 16 + (lane & 15);
      a[m] = *(bf16x8*)&H1s[r][kk ^ ((r & 7) << 3)];
    }
#pragma unroll
    for (int n = 0; n < 4; ++n) {
      int r = wc * 64 + n * 16 + (lane & 15);
      b[n] = *(bf16x8*)&Ws[r][kk ^ ((r & 7) << 3)];
    }
#pragma unroll
    for (int m = 0; m < 2; ++m)
#pragma unroll
      for (int n = 0; n < 4; ++n)
        acc[m][n] = __builtin_amdgcn_mfma_f32_16x16x32_bf16(a[m], b[n], acc[m][n], 0, 0, 0);
  }
#pragma unroll
  for (int m = 0; m < 2; ++m) {
    int rbase = row0 + wr * 32 + m * 16 + (lane >> 4) * 4;
#pragma unroll
    for (int n = 0; n < 4; ++n) {
      int col = wc * 64 + n * 16 + (lane & 15);
      float bb = b2[col];
#pragma unroll
      for (int r = 0; r < 4; ++r) {
        int row = rbase + r;
        if (row < N) {
          float v = fmaxf(acc[m][n][r] + bb, 0.f);
          hout[(size_t)row * 128 + col] = bf_rne(v);
        }
      }
    }
  }
}

// ---- bf16-A MFMA GEMM (classifier lin1): split W --------------------------
template <int RELU, int OUT_BF16, int SPLITW>
__global__ __launch_bounds__(256) void k_mgemm(const ushort* __restrict__ A,
                                               const ushort* __restrict__ Wt_hi,
                                               const ushort* __restrict__ Wt_lo,
                                               const float* __restrict__ bias,
                                               void* __restrict__ Cout,
                                               int M, int N, int K) {
  __shared__ ushort As[64][128];
  __shared__ ushort Ws_hi[64][128];
  __shared__ ushort Ws_lo[SPLITW ? 64 : 1][SPLITW ? 128 : 1];
  int tid = threadIdx.x;
  int row0 = blockIdx.y * 64, col0 = blockIdx.x * 64;
  int w = tid >> 6, lane = tid & 63;
  int wr = w >> 1, wc = w & 1;
  f32x4 acc[2][2] = {};
  int nk = K >> 7;
  for (int kc = 0; kc < nk; ++kc) {
    int k0 = kc << 7;
    if (kc) __syncthreads();
#pragma unroll
    for (int i = 0; i < 4; ++i) {
      int f = i * 256 + tid;
      int r = f >> 4, c8 = (f & 15) * 8;
      int ksw = c8 ^ ((r & 7) << 3);
      if (row0 + r < M) {
        *(bf16x8*)&As[r][ksw] = *(const bf16x8*)&A[(size_t)(row0 + r) * K + k0 + c8];
      } else {
        ushort4 z = {0, 0, 0, 0};
        *(ushort4*)&As[r][ksw] = z;
        *(ushort4*)&As[r][ksw + 4] = z;
      }
    }
#pragma unroll
    for (int i = 0; i < 4; ++i) {
      int f = i * 256 + tid;
      int r = f >> 4, c8 = (f & 15) * 8;
      int ksw = c8 ^ ((r & 7) << 3);
      *(bf16x8*)&Ws_hi[r][ksw] = *(const bf16x8*)&Wt_hi[(size_t)(col0 + r) * K + k0 + c8];
      if (SPLITW)
        *(bf16x8*)&Ws_lo[r][ksw] = *(const bf16x8*)&Wt_lo[(size_t)(col0 + r) * K + k0 + c8];
    }
    __syncthreads();
#pragma unroll
    for (int ks = 0; ks < 4; ++ks) {
      int kk = ks * 32 + (lane >> 4) * 8;
      bf16x8 a[2], bh[2], bl[2];
#pragma unroll
      for (int m = 0; m < 2; ++m) {
        int r = wr * 32 + m * 16 + (lane & 15);
        a[m] = *(bf16x8*)&As[r][kk ^ ((r & 7) << 3)];
      }
#pragma unroll
      for (int n = 0; n < 2; ++n) {
        int r = wc * 32 + n * 16 + (lane & 15);
        int ksw = kk ^ ((r & 7) << 3);
        bh[n] = *(bf16x8*)&Ws_hi[r][ksw];
        if (SPLITW) bl[n] = *(bf16x8*)&Ws_lo[r][ksw];
      }
#pragma unroll
      for (int m = 0; m < 2; ++m)
#pragma unroll
        for (int n = 0; n < 2; ++n) {
          acc[m][n] = __builtin_amdgcn_mfma_f32_16x16x32_bf16(a[m], bh[n], acc[m][n], 0, 0, 0);
          if (SPLITW)
            acc[m][n] = __builtin_amdgcn_mfma_f32_16x16x32_bf16(a[m], bl[n], acc[m][n], 0, 0, 0);
        }
    }
  }
#pragma unroll
  for (int m = 0; m < 2; ++m) {
    int rbase = row0 + wr * 32 + m * 16 + (lane >> 4) * 4;
#pragma unroll
    for (int n = 0; n < 2; ++n) {
      int col = col0 + wc * 32 + n * 16 + (lane & 15);
      float b = bias[col];
#pragma unroll
      for (int r = 0; r < 4; ++r) {
        int row = rbase + r;
        if (row < M) {
          float v = acc[m][n][r] + b;
          if (RELU) v = fmaxf(v, 0.f);
          if (OUT_BF16)
            ((ushort*)Cout)[(size_t)row * N + col] = bf_rne(v);
          else
            ((float*)Cout)[(size_t)row * N + col] = v;
        }
      }
    }
  }
}

// ---- batched per-graph pooling: all 6 slots in one dispatch ---------------
__global__ __launch_bounds__(128) void k_pool_all(
    const ushort* __restrict__ f0, const ushort* __restrict__ f1,
    const ushort* __restrict__ f2, const ushort* __restrict__ f3,
    const ushort* __restrict__ f4, const ushort* __restrict__ f5,
    const int* __restrict__ batch, ushort* __restrict__ pg, int N, int L1) {
  __shared__ float red[2][64][2];
  int g = blockIdx.x;
  int slot = blockIdx.y;
  const ushort* feat;
  switch (slot) {
    case 0: feat = f0; break;
    case 1: feat = f1; break;
    case 2: feat = f2; break;
    case 3: feat = f3; break;
    case 4: feat = f4; break;
    default: feat = f5; break;
  }
  int w = threadIdx.x >> 6, lane = threadIdx.x & 63;
  int lo = 0, hi = N;
  while (lo < hi) {
    int mid = (lo + hi) >> 1;
    if (batch[mid] < g) lo = mid + 1; else hi = mid;
  }
  int s = lo;
  hi = N;
  while (lo < hi) {
    int mid = (lo + hi) >> 1;
    if (batch[mid] < g + 1) lo = mid + 1; else hi = mid;
  }
  int e = lo;
  float a0 = 0.f, a1 = 0.f;
#pragma unroll 4
  for (int v = s + w; v < e; v += 2) {
    unsigned u = __builtin_nontemporal_load((const unsigned*)&feat[(size_t)v * 128 + lane * 2]);
    a0 += bf2f_lo(u);
    a1 += bf2f_hi(u);
  }
  red[w][lane][0] = a0;
  red[w][lane][1] = a1;
  __syncthreads();
  if (w == 0) {
    a0 = red[0][lane][0] + red[1][lane][0];
    a1 = red[0][lane][1] + red[1][lane][1];
    unsigned outw = (unsigned)bf_rne(a0) | ((unsigned)bf_rne(a1) << 16);
    *(unsigned*)&pg[((size_t)g * L1 + slot) * 128 + lane * 2] = outw;
  }
}

// ---- lin2 (768 -> C) + softmax, one wave per graph ------------------------
__global__ __launch_bounds__(64) void k_lin2_softmax(const float* __restrict__ A,
                                                     const float* __restrict__ W,
                                                     const float* __restrict__ b,
                                                     float* __restrict__ out, int K, int C) {
  constexpr int CMAX = 16;
  int g = blockIdx.x;
  int lane = threadIdx.x;
  float acc[CMAX];
#pragma unroll
  for (int c = 0; c < CMAX; ++c) acc[c] = 0.f;
  for (int k = lane; k < K; k += 64) {
    float a = A[(size_t)g * K + k];
#pragma unroll
    for (int c = 0; c < CMAX; ++c)
      if (c < C) acc[c] = fmaf(a, W[(size_t)k * C + c], acc[c]);
  }
#pragma unroll
  for (int off = 32; off; off >>= 1)
#pragma unroll
    for (int c = 0; c < CMAX; ++c) acc[c] += __shfl_xor(acc[c], off, 64);
  if (lane == 0) {
    float mx = -3.0e38f;
#pragma unroll
    for (int c = 0; c < CMAX; ++c)
      if (c < C) {
        acc[c] += b[c];
        mx = fmaxf(mx, acc[c]);
      }
    float sum = 0.f;
#pragma unroll
    for (int c = 0; c < CMAX; ++c)
      if (c < C) {
        acc[c] = expf(acc[c] - mx);
        sum += acc[c];
      }
    float inv = 1.f / sum;
#pragma unroll
    for (int c = 0; c < CMAX; ++c)
      if (c < C) out[(size_t)g * C + c] = acc[c] * inv;
  }
}

// ---------------------------------------------------------------------------
extern "C" void kernel_launch(void* const* d_in, const int* in_sizes, int n_in,
                              void* d_out, int out_size, void* d_ws, size_t ws_size,
                              hipStream_t stream) {
  const float* x     = (const float*)d_in[0];
  const int*   eidx  = (const int*)d_in[1];
  const float* emask = (const float*)d_in[2];
  const int*   batch = (const int*)d_in[3];
  const float* eps   = (const float*)d_in[5];
  const float* w1    = (const float*)d_in[6];
  const float* b1    = (const float*)d_in[7];
  const float* w2    = (const float*)d_in[8];
  const float* b2    = (const float*)d_in[9];
  const float* l1w   = (const float*)d_in[10];
  const float* l1b   = (const float*)d_in[11];
  const float* l2w   = (const float*)d_in[12];
  const float* l2b   = (const float*)d_in[13];

  const int N = in_sizes[3];          // 50000
  const int E = in_sizes[2];          // 800000
  const int L = in_sizes[5];          // 5
  const int D = in_sizes[0] / N;      // 128
  const int C = in_sizes[13];         // 10
  const int G = out_size / C;         // 512
  const int L1 = L + 1;
  const int H = in_sizes[7] / L;      // 128
  const int F = L1 * D;               // 768

  const int* src = eidx;
  const int* dst = eidx + E;

  // workspace carve (256B aligned)
  char* p = (char*)d_ws;
  auto carve = [&](size_t bytes) -> void* {
    void* r = (void*)p;
    p += (bytes + 255) & ~(size_t)255;
    return r;
  };
  int*    rowptr = (int*)carve((size_t)(N + 1) * 4);
  int*    cursor = (int*)carve((size_t)N * 4);
  int*    deg    = (int*)carve((size_t)N * 4);
  int*    excl   = (int*)carve((size_t)N * 4);
  int*    bsum   = (int*)carve(256 * 4);
  int2*   sedge  = (int2*)carve((size_t)E * 8);
  ushort* xb     = (ushort*)carve((size_t)N * D * 2);
  ushort* pooled = (ushort*)carve((size_t)N * D * 2);
  ushort* hb[5];
  for (int l = 0; l < 5; ++l) hb[l] = (ushort*)carve((size_t)N * D * 2);
  ushort* pg     = (ushort*)carve((size_t)G * F * 2);
  float*  l1out  = (float*)carve((size_t)G * F * 4);
  ushort* w1t_hi = (ushort*)carve((size_t)L * D * H * 2);
  ushort* w2t_hi = (ushort*)carve((size_t)L * H * D * 2);
  ushort* l1t_hi = (ushort*)carve((size_t)F * F * 2);
  ushort* l1t_lo = (ushort*)carve((size_t)F * F * 2);
  (void)ws_size;

  // CSR build (once; adjacency is layer-invariant)
  const int nb = ceil_div(N, 1024);
  hipMemsetAsync(deg, 0, (size_t)N * 4, stream);
  k_hist<<<ceil_div(E, 256), 256, 0, stream>>>(src, deg, E);
  k_scan1<<<nb, 256, 0, stream>>>(deg, excl, bsum, N);
  k_scan3<<<ceil_div(N, 256), 256, 0, stream>>>(excl, bsum, nb, rowptr, cursor, N);
  k_scatter<<<ceil_div(E, 256), 256, 0, stream>>>(src, dst, emask, cursor, sedge, E);

  // x -> bf16; all weight prep in one dispatch
  k_tobf16<<<ceil_div(N * D, 1024), 256, 0, stream>>>(x, xb, N * D);
  k_prep_all<<<dim3(F / 32, F / 32, 2 * L + 1), 256, 0, stream>>>(
      w1, w2, l1w, w1t_hi, w2t_hi, l1t_hi, l1t_lo, L, F);

  const ushort* h_in = xb;
  for (int l = 0; l < L; ++l) {
    k_agg<<<ceil_div(N, 2), 128, 0, stream>>>(h_in, rowptr, sedge, eps, l, pooled, N);
    k_mlp<<<ceil_div(N, 64), 256, 0, stream>>>(
        pooled, w1t_hi + (size_t)l * D * H, b1 + (size_t)l * H,
        w2t_hi + (size_t)l * H * D, b2 + (size_t)l * D, hb[l], N);
    h_in = hb[l];
  }

  // all 6 graph-pools in one dispatch
  k_pool_all<<<dim3(G, L1), 128, 0, stream>>>(xb, hb[0], hb[1], hb[2], hb[3], hb[4],
                                              batch, pg, N, L1);

  // classifier: lin1 (relu, K=768, split W), lin2 + softmax
  k_mgemm<1, 0, 1><<<dim3(F / 64, ceil_div(G, 64)), 256, 0, stream>>>(
      pg, l1t_hi, l1t_lo, l1b, l1out, G, F, F);
  k_lin2_softmax<<<G, 64, 0, stream>>>(l1out, l2w, l2b, (float*)d_out, F, C);
}

// Round 11
// 401.801 us; speedup vs baseline: 1.1442x; 1.1442x over previous
//
#include <hip/hip_runtime.h>

// ---------------------------------------------------------------------------
// GIN model. R11 = R9 base (421us) with R10's NT-hints reverted, plus:
//  - two-pass bucketed edge scatter replacing k_scatter (52us): every cache
//    line written wholly by one block -> ~20MB writes instead of E*64B=52MB.
//    Pass A: per-block LDS counting sort by src>>9 + contiguous run copy-out.
//    Pass B: one block per 512-node bucket, LDS cursors, block-local window.
//  - k_prep_all merged weight prep (kept; proven in R10)
// Requires N <= 65536 (bucket arrays sized 128). N=50000.
// Numerics: bf16 activations, RNE bf16 MLP W, split-bf16 lin1 W (absmax 0.0).
// ---------------------------------------------------------------------------

typedef __bf16 bf16x8 __attribute__((ext_vector_type(8)));
typedef float f32x4 __attribute__((ext_vector_type(4)));

static inline int ceil_div(int a, int b) { return (a + b - 1) / b; }

__device__ inline ushort bf_rne(float v) {
  unsigned u = __float_as_uint(v);
  return (ushort)((u + 0x7fffu + ((u >> 16) & 1u)) >> 16);
}
__device__ inline float bf2f(ushort u) { return __uint_as_float((unsigned)u << 16); }
__device__ inline float bf2f_lo(unsigned g) { return __uint_as_float(g << 16); }
__device__ inline float bf2f_hi(unsigned g) { return __uint_as_float(g & 0xffff0000u); }

// ---- CSR build ------------------------------------------------------------
__global__ void k_hist(const int* __restrict__ src, int* __restrict__ deg, int E) {
  int i = blockIdx.x * blockDim.x + threadIdx.x;
  if (i < E) atomicAdd(&deg[src[i]], 1);
}

__global__ __launch_bounds__(256) void k_scan1(const int* __restrict__ deg,
                                               int* __restrict__ excl,
                                               int* __restrict__ bsum, int N) {
  __shared__ int tsum[256];
  int b = blockIdx.x, t = threadIdx.x;
  int base = b * 1024 + t * 4;
  int v0 = 0, v1 = 0, v2 = 0, v3 = 0;
  if (base + 3 < N) {
    int4 q = *(const int4*)&deg[base];
    v0 = q.x; v1 = q.y; v2 = q.z; v3 = q.w;
  } else {
    if (base + 0 < N) v0 = deg[base + 0];
    if (base + 1 < N) v1 = deg[base + 1];
    if (base + 2 < N) v2 = deg[base + 2];
    if (base + 3 < N) v3 = deg[base + 3];
  }
  tsum[t] = v0 + v1 + v2 + v3;
  __syncthreads();
  for (int off = 1; off < 256; off <<= 1) {
    int x = (t >= off) ? tsum[t - off] : 0;
    __syncthreads();
    tsum[t] += x;
    __syncthreads();
  }
  int pre = (t == 0) ? 0 : tsum[t - 1];
  if (base < N)     excl[base]     = pre;
  if (base + 1 < N) excl[base + 1] = pre + v0;
  if (base + 2 < N) excl[base + 2] = pre + v0 + v1;
  if (base + 3 < N) excl[base + 3] = pre + v0 + v1 + v2;
  if (t == 255) bsum[b] = tsum[255];
}

// merged: scans bsum (nb<=256) in LDS per block, applies offsets, and seeds
// the bucket cursors (bcursor[b] = rowptr[b<<9]) for the bucketed scatter.
__global__ __launch_bounds__(256) void k_scan3(const int* __restrict__ excl,
                                               const int* __restrict__ bsum, int nb,
                                               int* __restrict__ rowptr,
                                               int* __restrict__ bcursor, int N) {
  __shared__ int s[256];
  int t = threadIdx.x;
  s[t] = (t < nb) ? bsum[t] : 0;
  __syncthreads();
  for (int off = 1; off < 256; off <<= 1) {
    int x = (t >= off) ? s[t - off] : 0;
    __syncthreads();
    s[t] += x;
    __syncthreads();
  }
  int i = blockIdx.x * 256 + t;
  if (i < N) {
    int blk = i >> 10;
    int boff = blk ? s[blk - 1] : 0;
    int v = excl[i] + boff;
    rowptr[i] = v;
    if ((i & 511) == 0) bcursor[i >> 9] = v;
  }
  if (i == N - 1) rowptr[N] = s[nb - 1];
}

// ---- bucketed scatter pass A: LDS counting sort by src>>9, run copy-out ---
// 2048 edges/block. bsedge[pos] = {src, dst, mask_bits, bucket}.
__global__ __launch_bounds__(256) void k_scat_a(
    const int* __restrict__ src, const int* __restrict__ dst,
    const float* __restrict__ mask, int* __restrict__ bcursor,
    int4* __restrict__ bsedge, int E, int nbuck) {
  __shared__ int hist[128], basep[128], lcur[128], runst[128];
  __shared__ int4 stage[2048];  // 32 KB
  int tid = threadIdx.x;
  int e0 = blockIdx.x * 2048;
  int ecnt = min(2048, E - e0);
  for (int b = tid; b < nbuck; b += 256) hist[b] = 0;
  __syncthreads();
  int s[8], d[8], m[8];
#pragma unroll
  for (int q = 0; q < 8; ++q) {
    int idx = tid + q * 256;
    if (idx < ecnt) {
      s[q] = src[e0 + idx];
      d[q] = dst[e0 + idx];
      m[q] = __float_as_int(mask[e0 + idx]);
      atomicAdd(&hist[s[q] >> 9], 1);
    }
  }
  __syncthreads();
  if (tid == 0) {
    int run = 0;
    for (int b = 0; b < nbuck; ++b) {
      basep[b] = run;
      run += hist[b];
    }
  }
  __syncthreads();
  for (int b = tid; b < nbuck; b += 256) lcur[b] = basep[b];
  __syncthreads();
#pragma unroll
  for (int q = 0; q < 8; ++q) {
    int idx = tid + q * 256;
    if (idx < ecnt) {
      int b = s[q] >> 9;
      int slot = atomicAdd(&lcur[b], 1);
      stage[slot] = make_int4(s[q], d[q], m[q], b);
    }
  }
  __syncthreads();
  for (int b = tid; b < nbuck; b += 256)
    runst[b] = hist[b] ? atomicAdd(&bcursor[b], hist[b]) : 0;
  __syncthreads();
  for (int slot = tid; slot < ecnt; slot += 256) {
    int4 e = stage[slot];
    int pos = runst[e.w] + (slot - basep[e.w]);
    bsedge[pos] = e;
  }
}

// ---- bucketed scatter pass B: one block per 512-node bucket ---------------
__global__ __launch_bounds__(256) void k_scat_b(
    const int4* __restrict__ bsedge, const int* __restrict__ rowptr,
    int2* __restrict__ sedge, int N) {
  __shared__ int cur[512];
  int b = blockIdx.x;
  int n0 = b << 9;
  int n1 = min(n0 + 512, N);
  int tid = threadIdx.x;
  for (int i = tid; i < n1 - n0; i += 256) cur[i] = rowptr[n0 + i];
  __syncthreads();
  int e0 = rowptr[n0], e1 = rowptr[n1];
  for (int j = e0 + tid; j < e1; j += 256) {
    int4 e = bsedge[j];
    int p = atomicAdd(&cur[e.x - n0], 1);
    sedge[p] = make_int2(e.y, e.z);
  }
}

// ---- fp32 -> bf16 conversion ---------------------------------------------
__global__ __launch_bounds__(256) void k_tobf16(const float* __restrict__ in,
                                                ushort* __restrict__ out, int n) {
  int base = (blockIdx.x * 256 + threadIdx.x) * 4;
  if (base + 3 < n) {
    float4 v = *(const float4*)&in[base];
    ushort4 o;
    o.x = bf_rne(v.x); o.y = bf_rne(v.y); o.z = bf_rne(v.z); o.w = bf_rne(v.w);
    *(ushort4*)&out[base] = o;
  } else {
    for (int k = base; k < n; ++k) out[k] = bf_rne(in[k]);
  }
}

// ---- merged weight prep: z<2L -> MLP mats (4x4 tiles); z==2L -> lin1 ------
__global__ __launch_bounds__(256) void k_prep_all(
    const float* __restrict__ W1, const float* __restrict__ W2,
    const float* __restrict__ L1W,
    ushort* __restrict__ hi1, ushort* __restrict__ hi2,
    ushort* __restrict__ l1hi, ushort* __restrict__ l1lo, int L, int F) {
  __shared__ float t[32][33];
  int z = blockIdx.z;
  int tx = threadIdx.x & 31, ty = threadIdx.x >> 5;
  if (z < 2 * L) {
    if (blockIdx.x >= 4 || blockIdx.y >= 4) return;
    const float* Wm = (z < L) ? (W1 + (size_t)z * 128 * 128)
                              : (W2 + (size_t)(z - L) * 128 * 128);
    ushort* him = (z < L) ? (hi1 + (size_t)z * 128 * 128)
                          : (hi2 + (size_t)(z - L) * 128 * 128);
    int k0 = blockIdx.x * 32, n0 = blockIdx.y * 32;
#pragma unroll
    for (int r = 0; r < 32; r += 8)
      t[ty + r][tx] = Wm[(size_t)(k0 + ty + r) * 128 + n0 + tx];
    __syncthreads();
#pragma unroll
    for (int r = 0; r < 32; r += 8)
      him[(size_t)(n0 + ty + r) * 128 + k0 + tx] = bf_rne(t[tx][ty + r]);
  } else {
    int k0 = blockIdx.x * 32, n0 = blockIdx.y * 32;
#pragma unroll
    for (int r = 0; r < 32; r += 8)
      t[ty + r][tx] = L1W[(size_t)(k0 + ty + r) * F + n0 + tx];
    __syncthreads();
#pragma unroll
    for (int r = 0; r < 32; r += 8) {
      float v = t[tx][ty + r];
      size_t o = (size_t)(n0 + ty + r) * F + k0 + tx;
      ushort h = bf_rne(v);
      l1hi[o] = h;
      l1lo[o] = bf_rne(v - bf2f(h));
    }
  }
}

// ---- per-node aggregation: 1 wave per node (R9 version, plain loads) ------
__global__ __launch_bounds__(128) void k_agg(const ushort* __restrict__ h,
                                             const int* __restrict__ rowptr,
                                             const int2* __restrict__ sedge,
                                             const float* __restrict__ eps, int layer,
                                             ushort* __restrict__ pooled, int N) {
  int v = blockIdx.x * 2 + (threadIdx.x >> 6);
  int lane = threadIdx.x & 63;
  if (v >= N) return;
  int beg = rowptr[v], end = rowptr[v + 1];
  float ax[8] = {}, ay[8] = {};
  int j = beg;
  for (; j + 8 <= end; j += 8) {
    int2 e[8];
    unsigned g[8];
#pragma unroll
    for (int q = 0; q < 8; ++q) e[q] = sedge[j + q];
#pragma unroll
    for (int q = 0; q < 8; ++q)
      g[q] = *(const unsigned*)&h[(size_t)e[q].x * 128 + lane * 2];
#pragma unroll
    for (int q = 0; q < 8; ++q) {
      float m = __int_as_float(e[q].y);
      ax[q] = fmaf(m, bf2f_lo(g[q]), ax[q]);
      ay[q] = fmaf(m, bf2f_hi(g[q]), ay[q]);
    }
  }
  for (; j + 2 <= end; j += 2) {
    int2 e0 = sedge[j], e1 = sedge[j + 1];
    unsigned g0 = *(const unsigned*)&h[(size_t)e0.x * 128 + lane * 2];
    unsigned g1 = *(const unsigned*)&h[(size_t)e1.x * 128 + lane * 2];
    ax[0] = fmaf(__int_as_float(e0.y), bf2f_lo(g0), ax[0]);
    ay[0] = fmaf(__int_as_float(e0.y), bf2f_hi(g0), ay[0]);
    ax[1] = fmaf(__int_as_float(e1.y), bf2f_lo(g1), ax[1]);
    ay[1] = fmaf(__int_as_float(e1.y), bf2f_hi(g1), ay[1]);
  }
  if (j < end) {
    int2 e = sedge[j];
    unsigned g = *(const unsigned*)&h[(size_t)e.x * 128 + lane * 2];
    float m = __int_as_float(e.y);
    ax[0] = fmaf(m, bf2f_lo(g), ax[0]);
    ay[0] = fmaf(m, bf2f_hi(g), ay[0]);
  }
  float sx = ((ax[0] + ax[1]) + (ax[2] + ax[3])) + ((ax[4] + ax[5]) + (ax[6] + ax[7]));
  float sy = ((ay[0] + ay[1]) + (ay[2] + ay[3])) + ((ay[4] + ay[5]) + (ay[6] + ay[7]));
  float ep = 1.0f + eps[layer];
  unsigned gs = *(const unsigned*)&h[(size_t)v * 128 + lane * 2];
  sx = fmaf(ep, bf2f_lo(gs), sx);
  sy = fmaf(ep, bf2f_hi(gs), sy);
  unsigned outw = (unsigned)bf_rne(sx) | ((unsigned)bf_rne(sy) << 16);
  *(unsigned*)&pooled[(size_t)v * 128 + lane * 2] = outw;
}

// ---- fused 2-layer MLP (R9 version): A direct from global, 48KB LDS -------
__global__ __launch_bounds__(256) void k_mlp(
    const ushort* __restrict__ pooled,
    const ushort* __restrict__ w1t, const float* __restrict__ b1,
    const ushort* __restrict__ w2t, const float* __restrict__ b2,
    ushort* __restrict__ hout, int N) {
  __shared__ ushort Ws[128][128];
  __shared__ ushort H1s[64][128];
  int tid = threadIdx.x;
  int w = tid >> 6, lane = tid & 63;
  int row0 = blockIdx.x * 64;
  int wr = w >> 1, wc = w & 1;

#pragma unroll
  for (int i = 0; i < 8; ++i) {
    int f = i * 256 + tid;
    int r = f >> 4, c8 = (f & 15) * 8;
    *(bf16x8*)&Ws[r][c8 ^ ((r & 7) << 3)] = *(const bf16x8*)&w1t[(size_t)r * 128 + c8];
  }
  __syncthreads();

  f32x4 acc[2][4];
#pragma unroll
  for (int m = 0; m < 2; ++m)
#pragma unroll
    for (int n = 0; n < 4; ++n) acc[m][n] = (f32x4){0.f, 0.f, 0.f, 0.f};
#pragma unroll
  for (int ks = 0; ks < 4; ++ks) {
    int kk = ks * 32 + (lane >> 4) * 8;
    bf16x8 a[2], b[4];
#pragma unroll
    for (int m = 0; m < 2; ++m) {
      int arow = row0 + wr * 32 + m * 16 + (lane & 15);
      if (arow >= N) arow = N - 1;
      a[m] = *(const bf16x8*)&pooled[(size_t)arow * 128 + kk];
    }
#pragma unroll
    for (int n = 0; n < 4; ++n) {
      int r = wc * 64 + n * 16 + (lane & 15);
      b[n] = *(bf16x8*)&Ws[r][kk ^ ((r & 7) << 3)];
    }
#pragma unroll
    for (int m = 0; m < 2; ++m)
#pragma unroll
      for (int n = 0; n < 4; ++n)
        acc[m][n] = __builtin_amdgcn_mfma_f32_16x16x32_bf16(a[m], b[n], acc[m][n], 0, 0, 0);
  }
#pragma unroll
  for (int m = 0; m < 2; ++m) {
    int rbase = wr * 32 + m * 16 + (lane >> 4) * 4;
#pragma unroll
    for (int n = 0; n < 4; ++n) {
      int col = wc * 64 + n * 16 + (lane & 15);
      float bb = b1[col];
#pragma unroll
      for (int r = 0; r < 4; ++r) {
        int row = rbase + r;
        float v = fmaxf(acc[m][n][r] + bb, 0.f);
        H1s[row][col ^ ((row & 7) << 3)] = bf_rne(v);
      }
    }
  }
  __syncthreads();

#pragma unroll
  for (int i = 0; i < 8; ++i) {
    int f = i * 256 + tid;
    int r = f >> 4, c8 = (f & 15) * 8;
    *(bf16x8*)&Ws[r][c8 ^ ((r & 7) << 3)] = *(const bf16x8*)&w2t[(size_t)r * 128 + c8];
  }
  __syncthreads();

#pragma unroll
  for (int m = 0; m < 2; ++m)
#pragma unroll
    for (int n = 0; n < 4; ++n) acc[m][n] = (f32x4){0.f, 0.f, 0.f, 0.f};
#pragma unroll
  for (int ks = 0; ks < 4; ++ks) {
    int kk = ks * 32 + (lane >> 4) * 8;
    bf16x8 a[2], b[4];
#pragma unroll
    for (int m = 0; m < 2; ++m) {
      int r = wr * 32 + m * 16 + (lane & 15);
      a[m] = *(bf16x8*)&H1s[r][kk ^ ((r & 7) << 3)];
    }
#pragma unroll
    for (int n = 0; n < 4; ++n) {
      int r = wc * 64 + n * 16 + (lane & 15);
      b[n] = *(bf16x8*)&Ws[r][kk ^ ((r & 7) << 3)];
    }
#pragma unroll
    for (int m = 0; m < 2; ++m)
#pragma unroll
      for (int n = 0; n < 4; ++n)
        acc[m][n] = __builtin_amdgcn_mfma_f32_16x16x32_bf16(a[m], b[n], acc[m][n], 0, 0, 0);
  }
#pragma unroll
  for (int m = 0; m < 2; ++m) {
    int rbase = row0 + wr * 32 + m * 16 + (lane >> 4) * 4;
#pragma unroll
    for (int n = 0; n < 4; ++n) {
      int col = wc * 64 + n * 16 + (lane & 15);
      float bb = b2[col];
#pragma unroll
      for (int r = 0; r < 4; ++r) {
        int row = rbase + r;
        if (row < N) {
          float v = fmaxf(acc[m][n][r] + bb, 0.f);
          hout[(size_t)row * 128 + col] = bf_rne(v);
        }
      }
    }
  }
}

// ---- bf16-A MFMA GEMM (classifier lin1): split W --------------------------
template <int RELU, int OUT_BF16, int SPLITW>
__global__ __launch_bounds__(256) void k_mgemm(const ushort* __restrict__ A,
                                               const ushort* __restrict__ Wt_hi,
                                               const ushort* __restrict__ Wt_lo,
                                               const float* __restrict__ bias,
                                               void* __restrict__ Cout,
                                               int M, int N, int K) {
  __shared__ ushort As[64][128];
  __shared__ ushort Ws_hi[64][128];
  __shared__ ushort Ws_lo[SPLITW ? 64 : 1][SPLITW ? 128 : 1];
  int tid = threadIdx.x;
  int row0 = blockIdx.y * 64, col0 = blockIdx.x * 64;
  int w = tid >> 6, lane = tid & 63;
  int wr = w >> 1, wc = w & 1;
  f32x4 acc[2][2] = {};
  int nk = K >> 7;
  for (int kc = 0; kc < nk; ++kc) {
    int k0 = kc << 7;
    if (kc) __syncthreads();
#pragma unroll
    for (int i = 0; i < 4; ++i) {
      int f = i * 256 + tid;
      int r = f >> 4, c8 = (f & 15) * 8;
      int ksw = c8 ^ ((r & 7) << 3);
      if (row0 + r < M) {
        *(bf16x8*)&As[r][ksw] = *(const bf16x8*)&A[(size_t)(row0 + r) * K + k0 + c8];
      } else {
        ushort4 z = {0, 0, 0, 0};
        *(ushort4*)&As[r][ksw] = z;
        *(ushort4*)&As[r][ksw + 4] = z;
      }
    }
#pragma unroll
    for (int i = 0; i < 4; ++i) {
      int f = i * 256 + tid;
      int r = f >> 4, c8 = (f & 15) * 8;
      int ksw = c8 ^ ((r & 7) << 3);
      *(bf16x8*)&Ws_hi[r][ksw] = *(const bf16x8*)&Wt_hi[(size_t)(col0 + r) * K + k0 + c8];
      if (SPLITW)
        *(bf16x8*)&Ws_lo[r][ksw] = *(const bf16x8*)&Wt_lo[(size_t)(col0 + r) * K + k0 + c8];
    }
    __syncthreads();
#pragma unroll
    for (int ks = 0; ks < 4; ++ks) {
      int kk = ks * 32 + (lane >> 4) * 8;
      bf16x8 a[2], bh[2], bl[2];
#pragma unroll
      for (int m = 0; m < 2; ++m) {
        int r = wr * 32 + m * 16 + (lane & 15);
        a[m] = *(bf16x8*)&As[r][kk ^ ((r & 7) << 3)];
      }
#pragma unroll
      for (int n = 0; n < 2; ++n) {
        int r = wc * 32 + n * 16 + (lane & 15);
        int ksw = kk ^ ((r & 7) << 3);
        bh[n] = *(bf16x8*)&Ws_hi[r][ksw];
        if (SPLITW) bl[n] = *(bf16x8*)&Ws_lo[r][ksw];
      }
#pragma unroll
      for (int m = 0; m < 2; ++m)
#pragma unroll
        for (int n = 0; n < 2; ++n) {
          acc[m][n] = __builtin_amdgcn_mfma_f32_16x16x32_bf16(a[m], bh[n], acc[m][n], 0, 0, 0);
          if (SPLITW)
            acc[m][n] = __builtin_amdgcn_mfma_f32_16x16x32_bf16(a[m], bl[n], acc[m][n], 0, 0, 0);
        }
    }
  }
#pragma unroll
  for (int m = 0; m < 2; ++m) {
    int rbase = row0 + wr * 32 + m * 16 + (lane >> 4) * 4;
#pragma unroll
    for (int n = 0; n < 2; ++n) {
      int col = col0 + wc * 32 + n * 16 + (lane & 15);
      float b = bias[col];
#pragma unroll
      for (int r = 0; r < 4; ++r) {
        int row = rbase + r;
        if (row < M) {
          float v = acc[m][n][r] + b;
          if (RELU) v = fmaxf(v, 0.f);
          if (OUT_BF16)
            ((ushort*)Cout)[(size_t)row * N + col] = bf_rne(v);
          else
            ((float*)Cout)[(size_t)row * N + col] = v;
        }
      }
    }
  }
}

// ---- batched per-graph pooling: all 6 slots in one dispatch ---------------
__global__ __launch_bounds__(128) void k_pool_all(
    const ushort* __restrict__ f0, const ushort* __restrict__ f1,
    const ushort* __restrict__ f2, const ushort* __restrict__ f3,
    const ushort* __restrict__ f4, const ushort* __restrict__ f5,
    const int* __restrict__ batch, ushort* __restrict__ pg, int N, int L1) {
  __shared__ float red[2][64][2];
  int g = blockIdx.x;
  int slot = blockIdx.y;
  const ushort* feat;
  switch (slot) {
    case 0: feat = f0; break;
    case 1: feat = f1; break;
    case 2: feat = f2; break;
    case 3: feat = f3; break;
    case 4: feat = f4; break;
    default: feat = f5; break;
  }
  int w = threadIdx.x >> 6, lane = threadIdx.x & 63;
  int lo = 0, hi = N;
  while (lo < hi) {
    int mid = (lo + hi) >> 1;
    if (batch[mid] < g) lo = mid + 1; else hi = mid;
  }
  int s = lo;
  hi = N;
  while (lo < hi) {
    int mid = (lo + hi) >> 1;
    if (batch[mid] < g + 1) lo = mid + 1; else hi = mid;
  }
  int e = lo;
  float a0 = 0.f, a1 = 0.f;
#pragma unroll 4
  for (int v = s + w; v < e; v += 2) {
    unsigned u = *(const unsigned*)&feat[(size_t)v * 128 + lane * 2];
    a0 += bf2f_lo(u);
    a1 += bf2f_hi(u);
  }
  red[w][lane][0] = a0;
  red[w][lane][1] = a1;
  __syncthreads();
  if (w == 0) {
    a0 = red[0][lane][0] + red[1][lane][0];
    a1 = red[0][lane][1] + red[1][lane][1];
    unsigned outw = (unsigned)bf_rne(a0) | ((unsigned)bf_rne(a1) << 16);
    *(unsigned*)&pg[((size_t)g * L1 + slot) * 128 + lane * 2] = outw;
  }
}

// ---- lin2 (768 -> C) + softmax, one wave per graph ------------------------
__global__ __launch_bounds__(64) void k_lin2_softmax(const float* __restrict__ A,
                                                     const float* __restrict__ W,
                                                     const float* __restrict__ b,
                                                     float* __restrict__ out, int K, int C) {
  constexpr int CMAX = 16;
  int g = blockIdx.x;
  int lane = threadIdx.x;
  float acc[CMAX];
#pragma unroll
  for (int c = 0; c < CMAX; ++c) acc[c] = 0.f;
  for (int k = lane; k < K; k += 64) {
    float a = A[(size_t)g * K + k];
#pragma unroll
    for (int c = 0; c < CMAX; ++c)
      if (c < C) acc[c] = fmaf(a, W[(size_t)k * C + c], acc[c]);
  }
#pragma unroll
  for (int off = 32; off; off >>= 1)
#pragma unroll
    for (int c = 0; c < CMAX; ++c) acc[c] += __shfl_xor(acc[c], off, 64);
  if (lane == 0) {
    float mx = -3.0e38f;
#pragma unroll
    for (int c = 0; c < CMAX; ++c)
      if (c < C) {
        acc[c] += b[c];
        mx = fmaxf(mx, acc[c]);
      }
    float sum = 0.f;
#pragma unroll
    for (int c = 0; c < CMAX; ++c)
      if (c < C) {
        acc[c] = expf(acc[c] - mx);
        sum += acc[c];
      }
    float inv = 1.f / sum;
#pragma unroll
    for (int c = 0; c < CMAX; ++c)
      if (c < C) out[(size_t)g * C + c] = acc[c] * inv;
  }
}

// ---------------------------------------------------------------------------
extern "C" void kernel_launch(void* const* d_in, const int* in_sizes, int n_in,
                              void* d_out, int out_size, void* d_ws, size_t ws_size,
                              hipStream_t stream) {
  const float* x     = (const float*)d_in[0];
  const int*   eidx  = (const int*)d_in[1];
  const float* emask = (const float*)d_in[2];
  const int*   batch = (const int*)d_in[3];
  const float* eps   = (const float*)d_in[5];
  const float* w1    = (const float*)d_in[6];
  const float* b1    = (const float*)d_in[7];
  const float* w2    = (const float*)d_in[8];
  const float* b2    = (const float*)d_in[9];
  const float* l1w   = (const float*)d_in[10];
  const float* l1b   = (const float*)d_in[11];
  const float* l2w   = (const float*)d_in[12];
  const float* l2b   = (const float*)d_in[13];

  const int N = in_sizes[3];          // 50000
  const int E = in_sizes[2];          // 800000
  const int L = in_sizes[5];          // 5
  const int D = in_sizes[0] / N;      // 128
  const int C = in_sizes[13];         // 10
  const int G = out_size / C;         // 512
  const int L1 = L + 1;
  const int H = in_sizes[7] / L;      // 128
  const int F = L1 * D;               // 768

  const int* src = eidx;
  const int* dst = eidx + E;

  // workspace carve (256B aligned)
  char* p = (char*)d_ws;
  auto carve = [&](size_t bytes) -> void* {
    void* r = (void*)p;
    p += (bytes + 255) & ~(size_t)255;
    return r;
  };
  int*    rowptr  = (int*)carve((size_t)(N + 1) * 4);
  int*    deg     = (int*)carve((size_t)N * 4);
  int*    excl    = (int*)carve((size_t)N * 4);
  int*    bsum    = (int*)carve(256 * 4);
  int*    bcursor = (int*)carve(256 * 4);
  int2*   sedge   = (int2*)carve((size_t)E * 8);
  int4*   bsedge  = (int4*)carve((size_t)E * 16);
  ushort* xb      = (ushort*)carve((size_t)N * D * 2);
  ushort* pooled  = (ushort*)carve((size_t)N * D * 2);
  ushort* hb[5];
  for (int l = 0; l < 5; ++l) hb[l] = (ushort*)carve((size_t)N * D * 2);
  ushort* pg      = (ushort*)carve((size_t)G * F * 2);
  float*  l1out   = (float*)carve((size_t)G * F * 4);
  ushort* w1t_hi  = (ushort*)carve((size_t)L * D * H * 2);
  ushort* w2t_hi  = (ushort*)carve((size_t)L * H * D * 2);
  ushort* l1t_hi  = (ushort*)carve((size_t)F * F * 2);
  ushort* l1t_lo  = (ushort*)carve((size_t)F * F * 2);
  (void)ws_size;

  // CSR build (once; adjacency is layer-invariant)
  const int nb = ceil_div(N, 1024);
  const int nbuck = ceil_div(N, 512);   // 98 (must be <=128)
  hipMemsetAsync(deg, 0, (size_t)N * 4, stream);
  k_hist<<<ceil_div(E, 256), 256, 0, stream>>>(src, deg, E);
  k_scan1<<<nb, 256, 0, stream>>>(deg, excl, bsum, N);
  k_scan3<<<ceil_div(N, 256), 256, 0, stream>>>(excl, bsum, nb, rowptr, bcursor, N);
  k_scat_a<<<ceil_div(E, 2048), 256, 0, stream>>>(src, dst, emask, bcursor, bsedge, E, nbuck);
  k_scat_b<<<nbuck, 256, 0, stream>>>(bsedge, rowptr, sedge, N);

  // x -> bf16; all weight prep in one dispatch
  k_tobf16<<<ceil_div(N * D, 1024), 256, 0, stream>>>(x, xb, N * D);
  k_prep_all<<<dim3(F / 32, F / 32, 2 * L + 1), 256, 0, stream>>>(
      w1, w2, l1w, w1t_hi, w2t_hi, l1t_hi, l1t_lo, L, F);

  const ushort* h_in = xb;
  for (int l = 0; l < L; ++l) {
    k_agg<<<ceil_div(N, 2), 128, 0, stream>>>(h_in, rowptr, sedge, eps, l, pooled, N);
    k_mlp<<<ceil_div(N, 64), 256, 0, stream>>>(
        pooled, w1t_hi + (size_t)l * D * H, b1 + (size_t)l * H,
        w2t_hi + (size_t)l * H * D, b2 + (size_t)l * D, hb[l], N);
    h_in = hb[l];
  }

  // all 6 graph-pools in one dispatch
  k_pool_all<<<dim3(G, L1), 128, 0, stream>>>(xb, hb[0], hb[1], hb[2], hb[3], hb[4],
                                              batch, pg, N, L1);

  // classifier: lin1 (relu, K=768, split W), lin2 + softmax
  k_mgemm<1, 0, 1><<<dim3(F / 64, ceil_div(G, 64)), 256, 0, stream>>>(
      pg, l1t_hi, l1t_lo, l1b, l1out, G, F, F);
  k_lin2_softmax<<<G, 64, 0, stream>>>(l1out, l2w, l2b, (float*)d_out, F, C);
}